// Round 12
// baseline (545.526 us; speedup 1.0000x reference)
//
#include <hip/hip_runtime.h>

typedef unsigned char u8;
typedef unsigned short u16;
typedef unsigned int u32;
typedef unsigned long long u64;
typedef long long i64;

#define TT 4
#define PH 4096             // pairs per half
#define KSW 16              // K/32 images for K=512
#define BNEPS 1e-5f

typedef __attribute__((ext_vector_type(8))) __bf16 bf16x8;
typedef __attribute__((ext_vector_type(4))) float f32x4;

__device__ __forceinline__ float bf2f(u16 b){ return __uint_as_float(((u32)b)<<16); }
__device__ __forceinline__ u16 f2bf_rne(float f){ u32 u = __float_as_uint(f); return (u16)((u + 0x7FFFu + ((u>>16)&1u))>>16); }
__device__ __forceinline__ u16 f2bf_tr(float f){ return (u16)(__float_as_uint(f)>>16); }

__device__ __forceinline__ void split2(float v, u16& h, u16& m){
    h = f2bf_tr(v); m = f2bf_tr(v - bf2f(h));
}

__device__ __forceinline__ f32x4 MFMA(bf16x8 a, bf16x8 b, f32x4 c){
    return __builtin_amdgcn_mfma_f32_16x16x32_bf16(a, b, c, 0, 0, 0);
}

union BF8 { u16 u[8]; bf16x8 v; };

__device__ __forceinline__ void gload16(const void* g, void* l){
    __builtin_amdgcn_global_load_lds(
        (const __attribute__((address_space(1))) unsigned int*)g,
        (__attribute__((address_space(3))) unsigned int*)l, 16, 0, 0);
}

// reg-staged kernels' swizzles (validated r3-r11)
__device__ __forceinline__ int swz(int row, int off){ return row*64 + (off ^ (((row>>1)&3)<<4)); }
__device__ __forceinline__ int swzK(int row, int off){ return row*128 + (off ^ ((row&7)<<4)); }
__device__ __forceinline__ int swzV(int row, int off){ return row*256 + (off ^ ((row&7)<<4)); }

__device__ __forceinline__ uint4 expand8(const u8* pb){
    u32 w0 = (pb[0]?0x3F80u:0u) | ((pb[1]?0x3F80u:0u)<<16);
    u32 w1 = (pb[2]?0x3F80u:0u) | ((pb[3]?0x3F80u:0u)<<16);
    u32 w2 = (pb[4]?0x3F80u:0u) | ((pb[5]?0x3F80u:0u)<<16);
    u32 w3 = (pb[6]?0x3F80u:0u) | ((pb[7]?0x3F80u:0u)<<16);
    return make_uint4(w0,w1,w2,w3);
}
__device__ __forceinline__ uint4 expandbits(u32 bits){
    u32 w0 = ((bits>>0)&1?0x3F80u:0u) | ((bits>>1)&1?0x3F800000u:0u);
    u32 w1 = ((bits>>2)&1?0x3F80u:0u) | ((bits>>3)&1?0x3F800000u:0u);
    u32 w2 = ((bits>>4)&1?0x3F80u:0u) | ((bits>>5)&1?0x3F800000u:0u);
    u32 w3 = ((bits>>6)&1?0x3F80u:0u) | ((bits>>7)&1?0x3F800000u:0u);
    return make_uint4(w0,w1,w2,w3);
}

// ---------------- W -> 256-col 1-plane RNE images: img(nb,ks)[g][col 0..255][16B], 16KB
__global__ __launch_bounds__(256)
void wsplit_rne(const float* __restrict__ W, u8* __restrict__ out, int NC, int nbOff, int ksn)
{
    const int ks = blockIdx.x, nbl = blockIdx.y;
    const int c0 = nbl*256;
    u8* img = out + ((i64)(nbOff+nbl)*ksn + ks)*16384;
    #pragma unroll
    for (int it=0; it<4; it++){
        int task = threadIdx.x + it*256;     // (col 0..255, gq minor 0..3)
        int col = task>>2, gq = task&3;
        float v[8];
        #pragma unroll
        for (int j=0;j<8;j++) v[j] = W[(i64)(ks*32 + gq*8 + j)*NC + c0 + col];
        u16 h[8];
        #pragma unroll
        for (int j=0;j<8;j++) h[j] = f2bf_rne(v[j]);
        int off = gq*4096 + col*16;
        *(ushort4*)(img + off)     = make_ushort4(h[0],h[1],h[2],h[3]);
        *(ushort4*)(img + off + 8) = make_ushort4(h[4],h[5],h[6],h[7]);
    }
}

// ---------------- W -> RNE bf16 [NC][K] (for p reg-staged GEMM)
__global__ __launch_bounds__(256)
void wsplit_old(const float* __restrict__ W, u16* __restrict__ out, int K, int NC)
{
    __shared__ float tile[64][65];
    const int k0 = blockIdx.x*64, c0 = blockIdx.y*64;
    const int tid = threadIdx.x;
    #pragma unroll
    for (int j=0;j<16;j++){
        int el = tid + j*256; int r = el>>6, c = el&63;
        tile[r][c] = W[(i64)(k0+r)*NC + c0 + c];
    }
    __syncthreads();
    #pragma unroll
    for (int j=0;j<16;j++){
        int el = tid + j*256; int c = el>>6, k = el&63;
        out[(i64)(c0+c)*K + k0 + k] = f2bf_rne(tile[k][c]);
    }
}

// ---------------- x -> A images: img(pb,ks)[pl][g][row 0..255][16B], row = pair*4 + t, 32KB
__global__ __launch_bounds__(256)
void asplitT(const float* __restrict__ x, u8* __restrict__ At, int pairBase)
{
    const int pb = blockIdx.x, ks = blockIdx.y;
    u8* img = At + ((i64)pb*KSW + ks)*32768;
    #pragma unroll
    for (int it=0; it<4; it++){
        int task = threadIdx.x + it*256;     // (row 0..255, gq minor)
        int row = task>>2, gq = task&3;
        int pair = row>>2, t = row&3;
        i64 grow = (i64)t*8192 + pairBase + pb*64 + pair;
        const float* src = x + grow*512 + ks*32 + gq*8;
        float4 f0 = *(const float4*)src, f1v = *(const float4*)(src+4);
        float vv[8] = {f0.x,f0.y,f0.z,f0.w,f1v.x,f1v.y,f1v.z,f1v.w};
        u16 h[8], m[8];
        #pragma unroll
        for (int j=0;j<8;j++) split2(vv[j], h[j], m[j]);
        int off = gq*4096 + row*16;
        *(ushort4*)(img + off)           = make_ushort4(h[0],h[1],h[2],h[3]);
        *(ushort4*)(img + off + 8)       = make_ushort4(h[4],h[5],h[6],h[7]);
        *(ushort4*)(img + 16384 + off)   = make_ushort4(m[0],m[1],m[2],m[3]);
        *(ushort4*)(img + 16384 + off+8) = make_ushort4(m[4],m[5],m[6],m[7]);
    }
}

// ---------------- 8-wave 256x256 GEMM + BN + LIF, 2-product (A_h+A_m)*RNE(W)
template<bool BITOUT>
__global__ __launch_bounds__(512,2)
void gemm8(const u8* __restrict__ At, const u8* __restrict__ Bt,
           const float* __restrict__ b0, const float* __restrict__ b1, const float* __restrict__ b2,
           const float* __restrict__ g0, const float* __restrict__ g1, const float* __restrict__ g2,
           const float* __restrict__ e0, const float* __restrict__ e1, const float* __restrict__ e2,
           const float* __restrict__ u0, const float* __restrict__ u1, const float* __restrict__ u2,
           const float* __restrict__ v0, const float* __restrict__ v1, const float* __restrict__ v2,
           u8* __restrict__ outp, int NB, int NCT, int cmask)
{
    extern __shared__ __align__(16) char smem[];     // 98304: 2 x (A 32K + B 16K)
    const int tid = threadIdx.x;
    const int cpx = gridDim.x >> 3;
    const int serial = (blockIdx.x & 7)*cpx + (blockIdx.x >> 3);
    const int pb = serial / NB, nb = serial % NB;

    const int w = tid>>6, lane = tid&63, g = lane>>4, ln = lane&15;
    const int wm = w>>2, wn = w&3;                   // 2M x 4N

    f32x4 acc[8][4];
    #pragma unroll
    for (int m=0;m<8;m++)
        #pragma unroll
        for (int cf=0;cf<4;cf++) acc[m][cf] = (f32x4)0.f;

    const u8* Ab = At + (i64)pb*KSW*32768;
    const u8* Bb = Bt + (i64)nb*KSW*16384;

    #pragma unroll
    for (int j=0;j<4;j++)
        gload16(Ab + j*8192 + tid*16, smem + j*8192 + tid*16);
    #pragma unroll
    for (int j=0;j<2;j++)
        gload16(Bb + j*8192 + tid*16, smem + 32768 + j*8192 + tid*16);
    __syncthreads();

    for (int ks=0; ks<KSW; ks++){
        char* cur = smem + (ks&1)*49152;
        char* nxt = smem + ((ks+1)&1)*49152;
        const bool pre = (ks+1 < KSW);
        const u8* Ai = Ab + (i64)(ks+1)*32768;
        const u8* Bi = Bb + (i64)(ks+1)*16384;

        if (pre){
            #pragma unroll
            for (int j=0;j<4;j++) gload16(Ai + j*8192 + tid*16, nxt + j*8192 + tid*16);
        }
        bf16x8 bfr[2][2];     // [b-half][cb]
        #pragma unroll
        for (int b=0;b<2;b++)
            #pragma unroll
            for (int cb=0;cb<2;cb++){
                int col = wn*64 + b*32 + cb*16 + ln;
                bfr[b][cb] = *(const bf16x8*)(cur + 32768 + g*4096 + col*16);
            }

        // ---- phase 0 (m-half a=0)
        {
            bf16x8 af[4][2];
            #pragma unroll
            for (int fm=0; fm<4; fm++){
                int row = wm*128 + 0*64 + fm*16 + ln;
                af[fm][0] = *(const bf16x8*)(cur + g*4096 + row*16);
                af[fm][1] = *(const bf16x8*)(cur + 16384 + g*4096 + row*16);
            }
            __builtin_amdgcn_s_setprio(1);
            #pragma unroll
            for (int fm=0; fm<4; fm++)
                #pragma unroll
                for (int b=0;b<2;b++)
                    #pragma unroll
                    for (int cb=0;cb<2;cb++){
                        const int m = 0*4+fm, cfi = b*2+cb;
                        f32x4 x4 = acc[m][cfi];
                        x4 = MFMA(af[fm][0], bfr[b][cb], x4);
                        x4 = MFMA(af[fm][1], bfr[b][cb], x4);
                        acc[m][cfi] = x4;
                    }
            __builtin_amdgcn_s_setprio(0);
        }
        __builtin_amdgcn_sched_barrier(0);
        if (pre){
            #pragma unroll
            for (int j=0;j<2;j++) gload16(Bi + j*8192 + tid*16, nxt + 32768 + j*8192 + tid*16);
        }
        // ---- phase 1 (m-half a=1)
        {
            bf16x8 af[4][2];
            #pragma unroll
            for (int fm=0; fm<4; fm++){
                int row = wm*128 + 1*64 + fm*16 + ln;
                af[fm][0] = *(const bf16x8*)(cur + g*4096 + row*16);
                af[fm][1] = *(const bf16x8*)(cur + 16384 + g*4096 + row*16);
            }
            __builtin_amdgcn_s_setprio(1);
            #pragma unroll
            for (int fm=0; fm<4; fm++)
                #pragma unroll
                for (int b=0;b<2;b++)
                    #pragma unroll
                    for (int cb=0;cb<2;cb++){
                        const int m = 1*4+fm, cfi = b*2+cb;
                        f32x4 x4 = acc[m][cfi];
                        x4 = MFMA(af[fm][0], bfr[b][cb], x4);
                        x4 = MFMA(af[fm][1], bfr[b][cb], x4);
                        acc[m][cfi] = x4;
                    }
            __builtin_amdgcn_s_setprio(0);
        }
        __syncthreads();
    }

    #pragma unroll
    for (int cf=0; cf<4; cf++){
        const int c = nb*256 + wn*64 + cf*16 + ln;
        int which = c >> 9; if (which > 2) which = 2;
        const float* bp = which==0?b0:(which==1?b1:b2);
        const float* gp = which==0?g0:(which==1?g1:g2);
        const float* ep = which==0?e0:(which==1?e1:e2);
        const float* up = which==0?u0:(which==1?u1:u2);
        const float* vp = which==0?v0:(which==1?v1:v2);
        const int ci = c & cmask;
        const float gs  = gp[ci] / sqrtf(vp[ci] + BNEPS);
        const float bf_ = bp[ci], muf = up[ci], bef = ep[ci];
        #pragma unroll
        for (int m=0; m<8; m++){
            const int rowBase = wm*128 + m*16 + g*4;
            const int prow = pb*64 + (rowBase>>2);
            float v = 0.f;
            #pragma unroll
            for (int t=0; t<TT; t++){
                float y = acc[m][cf][t] + bf_;
                float z = (y - muf) * gs + bef;
                v = v + (z - v) * 0.5f;
                float s = ((v - 1.0f) >= 0.f) ? 1.f : 0.f;
                if (BITOUT){
                    u64 bal = __ballot(s != 0.f);
                    if (ln == 0)
                        *(u16*)(outp + (i64)(t*PH + prow)*(NCT>>3) + ((nb*256 + wn*64 + cf*16)>>3)) = (u16)(bal >> (g*16));
                } else {
                    outp[((i64)t*PH + prow)*NCT + c] = (u8)s;
                }
                v = v * (1.f - s);
            }
        }
    }
}

// ---------------- f2 v3: BM=128 x BN=256, K=2048, grid 512 (2 blocks/CU), 8 waves 2Mx4N.
// T14 async-split staging: A-bits load + B DMA issued BEFORE compute; expand+ds_write AFTER.
__global__ __launch_bounds__(512,4)
void gemm8_f2(const u8* __restrict__ hh0, const u8* __restrict__ hh1,
              const u8* __restrict__ Bt,
              const float* __restrict__ bias, const float* __restrict__ gw,
              const float* __restrict__ bew,  const float* __restrict__ muw,
              const float* __restrict__ varw,
              const float* __restrict__ x,
              const u8* __restrict__ o20, const u8* __restrict__ o21,
              float* __restrict__ outF)
{
    __shared__ __align__(16) char smem[49152];       // 2 x (A 8K + B 16K)
    const int tid = threadIdx.x;
    const int cpx = gridDim.x >> 3;                  // 64
    const int serial = (blockIdx.x & 7)*cpx + (blockIdx.x >> 3);
    const int nb = serial & 1, pbg = serial >> 1;    // 256 pb-tiles x 2 nb
    const int half = pbg >> 7, pb = pbg & 127;       // 128 tiles of 32 pairs per half
    const u8* Abits = half ? hh1 : hh0;
    const u8* o2g   = half ? o21 : o20;

    const int w = tid>>6, lane = tid&63, g = lane>>4, ln = lane&15;
    const int wm = w>>2, wn = w&3;                   // 2M x 4N, wave 64x64

    f32x4 acc[4][4];
    #pragma unroll
    for (int fm=0;fm<4;fm++)
        #pragma unroll
        for (int cb=0;cb<4;cb++) acc[fm][cb] = (f32x4)0.f;

    const u8* Bb = Bt + (i64)nb*64*16384;
    const int aRow = tid>>2, aGq = tid&3;
    const i64 aGrow = (i64)(aRow&3)*PH + pb*32 + (aRow>>2);

    // prologue: tile 0
    {
        u32 b40 = *(const u32*)(Abits + aGrow*256);
        *(uint4*)(smem + swz(aRow, aGq*16)) = expandbits(b40 >> (8*aGq));
    }
    #pragma unroll
    for (int j=0;j<2;j++)
        gload16(Bb + (tid + j*512)*16, smem + 8192 + (tid + j*512)*16);
    __syncthreads();

    for (int ks=0; ks<64; ks++){
        char* cur = smem + (ks&1)*24576;
        char* nxt = smem + ((ks+1)&1)*24576;
        const bool pre = (ks+1 < 64);
        u32 b4n = 0;
        if (pre){
            b4n = *(const u32*)(Abits + aGrow*256 + (ks+1)*4);   // issued early, used late
            #pragma unroll
            for (int j=0;j<2;j++)
                gload16(Bb + (i64)(ks+1)*16384 + (tid+j*512)*16, nxt + 8192 + (tid+j*512)*16);
        }
        bf16x8 bfr[4], af[4];
        #pragma unroll
        for (int cb=0;cb<4;cb++)
            bfr[cb] = *(const bf16x8*)(cur + 8192 + g*4096 + (wn*64 + cb*16 + ln)*16);
        #pragma unroll
        for (int fm=0;fm<4;fm++)
            af[fm] = *(const bf16x8*)(cur + swz(wm*64 + fm*16 + ln, g*16));
        __builtin_amdgcn_s_setprio(1);
        #pragma unroll
        for (int fm=0;fm<4;fm++)
            #pragma unroll
            for (int cb=0;cb<4;cb++)
                acc[fm][cb] = MFMA(af[fm], bfr[cb], acc[fm][cb]);
        __builtin_amdgcn_s_setprio(0);
        if (pre)
            *(uint4*)(nxt + swz(aRow, aGq*16)) = expandbits(b4n >> (8*aGq));
        __syncthreads();
    }

    // epilogue: BN + LIF + (x + o2) + spike -> f32 out
    #pragma unroll
    for (int cb=0; cb<4; cb++){
        const int c = nb*256 + wn*64 + cb*16 + ln;
        const float gs  = gw[c] / sqrtf(varw[c] + BNEPS);
        const float bf_ = bias[c], muf = muw[c], bef = bew[c];
        #pragma unroll
        for (int fm=0; fm<4; fm++){
            const int prow = pb*32 + wm*16 + fm*4 + g;
            float v = 0.f;
            #pragma unroll
            for (int t=0; t<TT; t++){
                float y = acc[fm][cb][t] + bf_;
                float z = (y - muf) * gs + bef;
                v = v + (z - v) * 0.5f;
                float s = ((v - 1.0f) >= 0.f) ? 1.f : 0.f;
                i64 lrow = (i64)t*PH + prow;
                i64 grow = (i64)t*8192 + half*PH + prow;
                float xv = x[grow*512 + c];
                float o2v = (float)o2g[lrow*512 + c];
                outF[grow*512 + c] = (xv + o2v) + s;
                v = v * (1.f - s);
            }
        }
    }
}

// ---------------- p stage: T14-prefetched reg staging; spikes x W GEMM + BN + LIF
//                  -> o2 (global) + f1 A-images (x+o2 split)
__global__ __launch_bounds__(256)
void gemm_p(const u8* __restrict__ Au8, const u16* __restrict__ WT,
            const float* __restrict__ bias, const float* __restrict__ gw,
            const float* __restrict__ bew,  const float* __restrict__ muw,
            const float* __restrict__ varw,
            const float* __restrict__ x, u8* __restrict__ o2g,
            u8* __restrict__ At, int pairBase)
{
    __shared__ __align__(16) char smem[16384];
    char* smA = smem;
    char* smB = smem + 8192;
    const int tid = threadIdx.x;
    const int nbp = blockIdx.x, pbp = blockIdx.y;
    const int c0 = nbp*128, pair0 = pbp*32;
    const int w = tid>>6, l = tid&63, g = l>>4, ln = l&15;
    const int wm = w>>1, wn = w&1;

    const int sRow = tid>>1, sHalf = tid&1;
    const i64 sGrow = (i64)(sRow>>5)*PH + pair0 + (sRow&31);

    f32x4 acc[TT][4];
    #pragma unroll
    for (int t=0;t<TT;t++)
        #pragma unroll
        for (int cf=0;cf<4;cf++) acc[t][cf] = (f32x4)0.f;

    uint4 aReg, bReg[2];
    auto loadAB = [&](int k0){
        aReg = *(const uint4*)(Au8 + sGrow*512 + k0 + sHalf*16);
        #pragma unroll
        for (int j=0;j<2;j++){
            int cid = tid + j*256;
            int col = cid>>2, c = cid&3;
            bReg[j] = *(const uint4*)(WT + (i64)(c0+col)*512 + k0 + c*8);
        }
    };
    auto writeAB = [&](){
        const u8* pbb = (const u8*)&aReg;
        *(uint4*)(smA + swz(sRow, sHalf*32))    = expand8(pbb);
        *(uint4*)(smA + swz(sRow, sHalf*32+16)) = expand8(pbb+8);
        #pragma unroll
        for (int j=0;j<2;j++){
            int cid = tid + j*256;
            int col = cid>>2, c = cid&3;
            *(uint4*)(smB + swz(col, c*16)) = bReg[j];
        }
    };

    loadAB(0); writeAB(); __syncthreads();
    for (int k0 = 0; k0 < 512; k0 += 32){
        const bool pre = (k0+32 < 512);
        if (pre) loadAB(k0+32);              // issued early, used after compute
        bf16x8 bfr[4];
        #pragma unroll
        for (int cf=0;cf<4;cf++)
            bfr[cf] = *(const bf16x8*)(smB + swz(wn*64 + cf*16 + ln, g*16));
        #pragma unroll
        for (int t=0;t<TT;t++){
            bf16x8 afr = *(const bf16x8*)(smA + swz(t*32 + wm*16 + ln, g*16));
            #pragma unroll
            for (int cf=0;cf<4;cf++)
                acc[t][cf] = MFMA(afr, bfr[cf], acc[t][cf]);
        }
        __syncthreads();                     // reads of smA/smB done
        if (pre){ writeAB(); }
        __syncthreads();                     // writes visible
    }

    u8* tile = (u8*)smem;
    #pragma unroll
    for (int cf=0;cf<4;cf++){
        const int c = c0 + wn*64 + cf*16 + ln;
        const float gs  = gw[c] / sqrtf(varw[c] + BNEPS);
        const float bf_ = bias[c], muf = muw[c], bef = bew[c];
        #pragma unroll
        for (int r=0;r<4;r++){
            const int rl = wm*16 + g*4 + r;
            float v = 0.f;
            #pragma unroll
            for (int t=0;t<TT;t++){
                float y = acc[t][cf][r] + bf_;
                float z = (y - muf) * gs + bef;
                v = v + (z - v) * 0.5f;
                float s = ((v - 1.0f) >= 0.f) ? 1.f : 0.f;
                tile[t*4096 + rl*128 + (wn*64 + cf*16 + ln)] = (u8)s;
                v = v * (1.f - s);
            }
        }
    }
    __syncthreads();

    const int pbImg = pbp>>1, rOff = (pbp&1)*128;
    #pragma unroll
    for (int it=0; it<8; it++){
        int task = tid + it*256;
        int kq = task>>9, rem = task&511, gq = rem>>7, rowL = rem&127;
        int rl = rowL>>2, t = rowL&3;
        int ksAbs = nbp*4 + kq;
        int cL = kq*32 + gq*8;
        uint2 ob = *(const uint2*)(tile + t*4096 + rl*128 + cL);
        const u8* pbb = (const u8*)&ob;
        i64 grow = (i64)t*8192 + pairBase + pair0 + rl;
        const float* src = x + grow*512 + ksAbs*32 + gq*8;
        float4 f0 = *(const float4*)src, f1v = *(const float4*)(src+4);
        float vv[8] = {f0.x,f0.y,f0.z,f0.w,f1v.x,f1v.y,f1v.z,f1v.w};
        #pragma unroll
        for (int j=0;j<8;j++) vv[j] = vv[j] + (float)pbb[j];
        u16 h[8], m[8];
        #pragma unroll
        for (int j=0;j<8;j++) split2(vv[j], h[j], m[j]);
        u8* img = At + ((i64)pbImg*KSW + ksAbs)*32768;
        int off = gq*4096 + (rOff + rowL)*16;
        *(ushort4*)(img + off)           = make_ushort4(h[0],h[1],h[2],h[3]);
        *(ushort4*)(img + off + 8)       = make_ushort4(h[4],h[5],h[6],h[7]);
        *(ushort4*)(img + 16384 + off)   = make_ushort4(m[0],m[1],m[2],m[3]);
        *(ushort4*)(img + 16384 + off+8) = make_ushort4(m[4],m[5],m[6],m[7]);
        *(uint2*)(o2g + ((i64)t*PH + pair0 + rl)*512 + ksAbs*32 + gq*8) = ob;
    }
}

// ---------------- spiking attention + attn-LIF (v_th=0.5), qkv packed stride 1536
__global__ __launch_bounds__(256)
void attn_lif_kernel(const u8* __restrict__ qkv, u8* __restrict__ os)
{
    __shared__ __align__(16) char smem[49152];
    char* Kl = smem;
    char* VT = smem + 16384;
    char* AT = smem + 32768;

    const int tid = threadIdx.x;
    const int w = tid>>6, l = tid&63, g = l>>4, ln = l&15;
    const int h = blockIdx.y, b = blockIdx.z;
    const int n0 = blockIdx.x*64 + w*16;

    f32x4 vmem[4];
    #pragma unroll
    for (int cf=0;cf<4;cf++) vmem[cf] = (f32x4)0.f;

    for (int t=0;t<TT;t++){
        const i64 tb = ((i64)(t*16 + b)*256)*1536;
        const i64 ob = ((i64)(t*16 + b)*256)*512 + h*64;
        bf16x8 qf[2];
        #pragma unroll
        for (int ksl=0;ksl<2;ksl++){
            uint2 qv = *(const uint2*)(qkv + tb + (i64)(n0+ln)*1536 + h*64 + ksl*32 + g*8);
            const u8* pb = (const u8*)&qv;
            BF8 f;
            #pragma unroll
            for (int j=0;j<8;j++) f.u[j] = pb[j] ? 0x3F80 : 0;
            qf[ksl] = f.v;
        }
        f32x4 oacc[4];
        #pragma unroll
        for (int cf=0;cf<4;cf++) oacc[cf] = (f32x4)0.f;

        for (int mh=0; mh<2; mh++){
            __syncthreads();
            {
                const int lm = tid>>1, seg = tid&1;
                const u8* src = qkv + tb + (i64)(mh*128+lm)*1536 + 512 + h*64 + seg*32;
                uint4 a = *(const uint4*)(src), c = *(const uint4*)(src+16);
                const u8* pa = (const u8*)&a; const u8* pc = (const u8*)&c;
                #pragma unroll
                for (int q=0;q<4;q++){
                    *(ushort4*)(Kl + swzK(lm, seg*64 + q*8)) =
                        make_ushort4(pa[q*4]?0x3F80:0, pa[q*4+1]?0x3F80:0, pa[q*4+2]?0x3F80:0, pa[q*4+3]?0x3F80:0);
                    *(ushort4*)(Kl + swzK(lm, seg*64 + 32 + q*8)) =
                        make_ushort4(pc[q*4]?0x3F80:0, pc[q*4+1]?0x3F80:0, pc[q*4+2]?0x3F80:0, pc[q*4+3]?0x3F80:0);
                }
            }
            {
                const int lm = tid>>1, seg = tid&1;
                const u8* src = qkv + tb + (i64)(mh*128+lm)*1536 + 1024 + h*64 + seg*32;
                uint4 a = *(const uint4*)(src), c = *(const uint4*)(src+16);
                const u8* pa = (const u8*)&a; const u8* pc = (const u8*)&c;
                #pragma unroll
                for (int j=0;j<16;j++){
                    *(u16*)(VT + swzV(seg*32 + j,      lm*2)) = pa[j] ? 0x3F80 : 0;
                    *(u16*)(VT + swzV(seg*32 + 16 + j, lm*2)) = pc[j] ? 0x3F80 : 0;
                }
            }
            __syncthreads();
            #pragma unroll
            for (int rf=0;rf<8;rf++){
                f32x4 s = (f32x4)0.f;
                #pragma unroll
                for (int ksl=0;ksl<2;ksl++){
                    bf16x8 kf = *(const bf16x8*)(Kl + swzK(rf*16+ln, ksl*64 + g*16));
                    s = MFMA(kf, qf[ksl], s);
                }
                ushort4 pk = make_ushort4(f2bf_rne(s[0]*0.125f), f2bf_rne(s[1]*0.125f),
                                          f2bf_rne(s[2]*0.125f), f2bf_rne(s[3]*0.125f));
                *(ushort4*)(AT + swzV(w*16+ln, rf*32 + g*8)) = pk;
            }
            #pragma unroll
            for (int ms=0;ms<4;ms++){
                bf16x8 af = *(const bf16x8*)(AT + swzV(w*16+ln, ms*64 + g*16));
                #pragma unroll
                for (int cf=0;cf<4;cf++){
                    bf16x8 vf = *(const bf16x8*)(VT + swzV(cf*16+ln, ms*64 + g*16));
                    oacc[cf] = MFMA(af, vf, oacc[cf]);
                }
            }
        }
        #pragma unroll
        for (int cf=0;cf<4;cf++)
            #pragma unroll
            for (int r=0;r<4;r++){
                float v = vmem[cf][r];
                v = v + (oacc[cf][r] - v) * 0.5f;
                float s = ((v - 0.5f) >= 0.f) ? 1.f : 0.f;
                os[ob + (i64)(n0 + g*4 + r)*512 + cf*16 + ln] = (u8)s;
                vmem[cf][r] = v * (1.f - s);
            }
    }
}

extern "C" void kernel_launch(void* const* d_in, const int* in_sizes, int n_in,
                              void* d_out, int out_size, void* d_ws, size_t ws_size,
                              hipStream_t stream)
{
    (void)in_sizes; (void)n_in; (void)out_size; (void)ws_size;
    const float* x = (const float*)d_in[0];
    #define GETP(i) ((const float*)d_in[i])

    char* ws = (char*)d_ws;
    u8*  Bqkv = (u8*)(ws + 0);               //  6*16*16384 = 1,572,864
    u8*  Bf1  = (u8*)(ws + 1572864);         //  8*16*16384 = 2,097,152
    u8*  Bf2  = (u8*)(ws + 3670016);         //  2*64*16384 = 2,097,152
    u16* WTp  = (u16*)(ws + 5767168);        //  524,288
    u8*  At   = (u8*)(ws + 6291456);         // 64*16*32768 = 33,554,432
    u8*  qkv  = (u8*)(ws + 39845888);        // 25,165,824
    u8*  os_  = (u8*)(ws + 65011712);        //  8,388,608
    u8*  o2h[2] = { (u8*)(ws + 73400320), (u8*)(ws + 81788928) };   // 8,388,608 each
    u8*  hhb[2] = { (u8*)(ws + 90177536), (u8*)(ws + 94371840) };   // 4,194,304 each -> ends 98,566,144

    hipFuncSetAttribute((const void*)gemm8<false>, hipFuncAttributeMaxDynamicSharedMemorySize, 98304);
    hipFuncSetAttribute((const void*)gemm8<true>,  hipFuncAttributeMaxDynamicSharedMemorySize, 98304);

    dim3 blk(256,1,1);
    // W prep
    wsplit_rne<<<dim3(16,2), blk,0,stream>>>(GETP(1),  Bqkv, 512, 0, 16);
    wsplit_rne<<<dim3(16,2), blk,0,stream>>>(GETP(7),  Bqkv, 512, 2, 16);
    wsplit_rne<<<dim3(16,2), blk,0,stream>>>(GETP(13), Bqkv, 512, 4, 16);
    wsplit_rne<<<dim3(16,8), blk,0,stream>>>(GETP(25), Bf1, 2048, 0, 16);
    wsplit_rne<<<dim3(64,2), blk,0,stream>>>(GETP(31), Bf2,  512, 0, 64);
    wsplit_old<<<dim3(8,8),  blk,0,stream>>>(GETP(19), WTp,  512, 512);

    for (int hb = 0; hb < 2; hb++){
        const int pb = hb * PH;
        asplitT<<<dim3(64,16),blk,0,stream>>>(x, At, pb);
        // fused q/k/v (N=1536, NB=6, grid 384)
        gemm8<false><<<dim3(384),dim3(512),98304,stream>>>(At, Bqkv,
            GETP(2),GETP(8),GETP(14),  GETP(3),GETP(9),GETP(15),
            GETP(4),GETP(10),GETP(16), GETP(5),GETP(11),GETP(17),
            GETP(6),GETP(12),GETP(18), qkv, 6, 1536, 511);
        attn_lif_kernel<<<dim3(4,8,16),blk,0,stream>>>(qkv, os_);
        // p stage + fused o2/f1-image production
        gemm_p<<<dim3(4,128),blk,0,stream>>>(os_, WTp,
            GETP(20),GETP(21),GETP(22),GETP(23),GETP(24), x, o2h[hb], At, pb);
        // f1 (N=2048, NB=8, grid 512, bitpacked out)
        gemm8<true><<<dim3(512),dim3(512),98304,stream>>>(At, Bf1,
            GETP(26),GETP(26),GETP(26), GETP(27),GETP(27),GETP(27),
            GETP(28),GETP(28),GETP(28), GETP(29),GETP(29),GETP(29),
            GETP(30),GETP(30),GETP(30), hhb[hb], 8, 2048, 2047);
    }
    // f2 v3: both halves, grid 512 (2 blocks/CU), T14 staging, fused final add -> d_out
    gemm8_f2<<<dim3(512),dim3(512),0,stream>>>(hhb[0], hhb[1], Bf2,
        GETP(32),GETP(33),GETP(34),GETP(35),GETP(36), x, o2h[0], o2h[1], (float*)d_out);
}

// Round 13
// 506.655 us; speedup vs baseline: 1.0767x; 1.0767x over previous
//
#include <hip/hip_runtime.h>

typedef unsigned char u8;
typedef unsigned short u16;
typedef unsigned int u32;
typedef unsigned long long u64;
typedef long long i64;

#define TT 4
#define PH 4096             // pairs per half
#define KSW 16              // K/32 images for K=512
#define BNEPS 1e-5f

typedef __attribute__((ext_vector_type(8))) __bf16 bf16x8;
typedef __attribute__((ext_vector_type(4))) float f32x4;

__device__ __forceinline__ float bf2f(u16 b){ return __uint_as_float(((u32)b)<<16); }
__device__ __forceinline__ u16 f2bf_rne(float f){ u32 u = __float_as_uint(f); return (u16)((u + 0x7FFFu + ((u>>16)&1u))>>16); }
__device__ __forceinline__ u16 f2bf_tr(float f){ return (u16)(__float_as_uint(f)>>16); }

__device__ __forceinline__ void split2(float v, u16& h, u16& m){
    h = f2bf_tr(v); m = f2bf_tr(v - bf2f(h));
}

__device__ __forceinline__ f32x4 MFMA(bf16x8 a, bf16x8 b, f32x4 c){
    return __builtin_amdgcn_mfma_f32_16x16x32_bf16(a, b, c, 0, 0, 0);
}

union BF8 { u16 u[8]; bf16x8 v; };

__device__ __forceinline__ void gload16(const void* g, void* l){
    __builtin_amdgcn_global_load_lds(
        (const __attribute__((address_space(1))) unsigned int*)g,
        (__attribute__((address_space(3))) unsigned int*)l, 16, 0, 0);
}

// reg-staged kernels' swizzles (validated r3-r12)
__device__ __forceinline__ int swz(int row, int off){ return row*64 + (off ^ (((row>>1)&3)<<4)); }
__device__ __forceinline__ int swzK(int row, int off){ return row*128 + (off ^ ((row&7)<<4)); }
__device__ __forceinline__ int swzV(int row, int off){ return row*256 + (off ^ ((row&7)<<4)); }

__device__ __forceinline__ uint4 expand8(const u8* pb){
    u32 w0 = (pb[0]?0x3F80u:0u) | ((pb[1]?0x3F80u:0u)<<16);
    u32 w1 = (pb[2]?0x3F80u:0u) | ((pb[3]?0x3F80u:0u)<<16);
    u32 w2 = (pb[4]?0x3F80u:0u) | ((pb[5]?0x3F80u:0u)<<16);
    u32 w3 = (pb[6]?0x3F80u:0u) | ((pb[7]?0x3F80u:0u)<<16);
    return make_uint4(w0,w1,w2,w3);
}
__device__ __forceinline__ uint4 expandbits(u32 bits){
    u32 w0 = ((bits>>0)&1?0x3F80u:0u) | ((bits>>1)&1?0x3F800000u:0u);
    u32 w1 = ((bits>>2)&1?0x3F80u:0u) | ((bits>>3)&1?0x3F800000u:0u);
    u32 w2 = ((bits>>4)&1?0x3F80u:0u) | ((bits>>5)&1?0x3F800000u:0u);
    u32 w3 = ((bits>>6)&1?0x3F80u:0u) | ((bits>>7)&1?0x3F800000u:0u);
    return make_uint4(w0,w1,w2,w3);
}

// ---------------- W -> CB-col 1-plane RNE images: img(nb,ks)[g][col 0..CB-1][16B], CB*64 bytes
__global__ __launch_bounds__(256)
void wsplit_rne(const float* __restrict__ W, u8* __restrict__ out, int NC, int nbOff, int ksn, int CB)
{
    const int ks = blockIdx.x, nbl = blockIdx.y;
    const int c0 = nbl*CB;
    u8* img = out + ((i64)(nbOff+nbl)*ksn + ks)*(i64)(CB*64);
    const int iters = CB >> 6;                  // tasks = CB*4, 256 threads
    for (int it=0; it<iters; it++){
        int task = threadIdx.x + it*256;        // (col, gq minor 0..3)
        int col = task>>2, gq = task&3;
        float v[8];
        #pragma unroll
        for (int j=0;j<8;j++) v[j] = W[(i64)(ks*32 + gq*8 + j)*NC + c0 + col];
        u16 h[8];
        #pragma unroll
        for (int j=0;j<8;j++) h[j] = f2bf_rne(v[j]);
        int off = gq*(CB*16) + col*16;
        *(ushort4*)(img + off)     = make_ushort4(h[0],h[1],h[2],h[3]);
        *(ushort4*)(img + off + 8) = make_ushort4(h[4],h[5],h[6],h[7]);
    }
}

// ---------------- W -> RNE bf16 [NC][K] (for p reg-staged GEMM)
__global__ __launch_bounds__(256)
void wsplit_old(const float* __restrict__ W, u16* __restrict__ out, int K, int NC)
{
    __shared__ float tile[64][65];
    const int k0 = blockIdx.x*64, c0 = blockIdx.y*64;
    const int tid = threadIdx.x;
    #pragma unroll
    for (int j=0;j<16;j++){
        int el = tid + j*256; int r = el>>6, c = el&63;
        tile[r][c] = W[(i64)(k0+r)*NC + c0 + c];
    }
    __syncthreads();
    #pragma unroll
    for (int j=0;j<16;j++){
        int el = tid + j*256; int c = el>>6, k = el&63;
        out[(i64)(c0+c)*K + k0 + k] = f2bf_rne(tile[k][c]);
    }
}

// ---------------- x -> A images: img(pb,ks)[pl][g][row 0..255][16B], row = pair*4 + t, 32KB
__global__ __launch_bounds__(256)
void asplitT(const float* __restrict__ x, u8* __restrict__ At, int pairBase)
{
    const int pb = blockIdx.x, ks = blockIdx.y;
    u8* img = At + ((i64)pb*KSW + ks)*32768;
    #pragma unroll
    for (int it=0; it<4; it++){
        int task = threadIdx.x + it*256;     // (row 0..255, gq minor)
        int row = task>>2, gq = task&3;
        int pair = row>>2, t = row&3;
        i64 grow = (i64)t*8192 + pairBase + pb*64 + pair;
        const float* src = x + grow*512 + ks*32 + gq*8;
        float4 f0 = *(const float4*)src, f1v = *(const float4*)(src+4);
        float vv[8] = {f0.x,f0.y,f0.z,f0.w,f1v.x,f1v.y,f1v.z,f1v.w};
        u16 h[8], m[8];
        #pragma unroll
        for (int j=0;j<8;j++) split2(vv[j], h[j], m[j]);
        int off = gq*4096 + row*16;
        *(ushort4*)(img + off)           = make_ushort4(h[0],h[1],h[2],h[3]);
        *(ushort4*)(img + off + 8)       = make_ushort4(h[4],h[5],h[6],h[7]);
        *(ushort4*)(img + 16384 + off)   = make_ushort4(m[0],m[1],m[2],m[3]);
        *(ushort4*)(img + 16384 + off+8) = make_ushort4(m[4],m[5],m[6],m[7]);
    }
}

// ---------------- gemm8 v2: BM=256 x BN=128, dbuf 2x(A 32K + B 8K) = 80KB -> 2 blocks/CU.
// 8 waves 4M x 2N (wave 64x64). 2-product (A_h+A_m)*RNE(W). BN=128 B-images.
template<bool BITOUT>
__global__ __launch_bounds__(512,4)
void gemm8(const u8* __restrict__ At, const u8* __restrict__ Bt,
           const float* __restrict__ b0, const float* __restrict__ b1, const float* __restrict__ b2,
           const float* __restrict__ g0, const float* __restrict__ g1, const float* __restrict__ g2,
           const float* __restrict__ e0, const float* __restrict__ e1, const float* __restrict__ e2,
           const float* __restrict__ u0, const float* __restrict__ u1, const float* __restrict__ u2,
           const float* __restrict__ v0, const float* __restrict__ v1, const float* __restrict__ v2,
           u8* __restrict__ outp, int NB, int NCT, int cmask)
{
    extern __shared__ __align__(16) char smem[];     // 81920: 2 x (A 32K + B 8K)
    const int tid = threadIdx.x;
    const int cpx = gridDim.x >> 3;
    const int serial = (blockIdx.x & 7)*cpx + (blockIdx.x >> 3);
    const int pb = serial / NB, nb = serial % NB;

    const int w = tid>>6, lane = tid&63, g = lane>>4, ln = lane&15;
    const int wm = w>>1, wn = w&1;                   // 4M x 2N, wave 64x64

    f32x4 acc[4][4];
    #pragma unroll
    for (int fm=0;fm<4;fm++)
        #pragma unroll
        for (int cb=0;cb<4;cb++) acc[fm][cb] = (f32x4)0.f;

    const u8* Ab = At + (i64)pb*KSW*32768;
    const u8* Bb = Bt + (i64)nb*KSW*8192;

    // prologue: stage tile 0 (A 32KB, B 8KB)
    #pragma unroll
    for (int j=0;j<4;j++)
        gload16(Ab + j*8192 + tid*16, smem + j*8192 + tid*16);
    gload16(Bb + tid*16, smem + 32768 + tid*16);
    __syncthreads();

    for (int ks=0; ks<KSW; ks++){
        char* cur = smem + (ks&1)*40960;
        char* nxt = smem + ((ks+1)&1)*40960;
        if (ks+1 < KSW){
            const u8* Ai = Ab + (i64)(ks+1)*32768;
            #pragma unroll
            for (int j=0;j<4;j++) gload16(Ai + j*8192 + tid*16, nxt + j*8192 + tid*16);
            gload16(Bb + (i64)(ks+1)*8192 + tid*16, nxt + 32768 + tid*16);
        }
        bf16x8 bfr[4];
        #pragma unroll
        for (int cb=0;cb<4;cb++){
            int col = wn*64 + cb*16 + ln;
            bfr[cb] = *(const bf16x8*)(cur + 32768 + g*2048 + col*16);
        }
        __builtin_amdgcn_s_setprio(1);
        #pragma unroll
        for (int fm=0; fm<4; fm++){
            int row = wm*64 + fm*16 + ln;
            bf16x8 a0 = *(const bf16x8*)(cur + g*4096 + row*16);
            bf16x8 a1 = *(const bf16x8*)(cur + 16384 + g*4096 + row*16);
            #pragma unroll
            for (int cb=0;cb<4;cb++){
                f32x4 x4 = acc[fm][cb];
                x4 = MFMA(a0, bfr[cb], x4);
                x4 = MFMA(a1, bfr[cb], x4);
                acc[fm][cb] = x4;
            }
        }
        __builtin_amdgcn_s_setprio(0);
        __syncthreads();
    }

    // epilogue: BN + LIF (acc components = the 4 t-steps of one (pair,col))
    #pragma unroll
    for (int cb=0; cb<4; cb++){
        const int c = nb*128 + wn*64 + cb*16 + ln;
        int which = c >> 9; if (which > 2) which = 2;
        const float* bp = which==0?b0:(which==1?b1:b2);
        const float* gp = which==0?g0:(which==1?g1:g2);
        const float* ep = which==0?e0:(which==1?e1:e2);
        const float* up = which==0?u0:(which==1?u1:u2);
        const float* vp = which==0?v0:(which==1?v1:v2);
        const int ci = c & cmask;
        const float gs  = gp[ci] / sqrtf(vp[ci] + BNEPS);
        const float bf_ = bp[ci], muf = up[ci], bef = ep[ci];
        #pragma unroll
        for (int fm=0; fm<4; fm++){
            const int prow = pb*64 + wm*16 + fm*4 + g;
            float v = 0.f;
            #pragma unroll
            for (int t=0; t<TT; t++){
                float y = acc[fm][cb][t] + bf_;
                float z = (y - muf) * gs + bef;
                v = v + (z - v) * 0.5f;
                float s = ((v - 1.0f) >= 0.f) ? 1.f : 0.f;
                if (BITOUT){
                    u64 bal = __ballot(s != 0.f);
                    if (ln == 0)
                        *(u16*)(outp + (i64)(t*PH + prow)*(NCT>>3) + ((nb*128 + wn*64 + cb*16)>>3)) = (u16)(bal >> (g*16));
                } else {
                    outp[((i64)t*PH + prow)*NCT + c] = (u8)s;
                }
                v = v * (1.f - s);
            }
        }
    }
}

// ---------------- f2 v3 (r12, kept): BM=128 x BN=256, K=2048, grid 512, T14 staging.
__global__ __launch_bounds__(512,4)
void gemm8_f2(const u8* __restrict__ hh0, const u8* __restrict__ hh1,
              const u8* __restrict__ Bt,
              const float* __restrict__ bias, const float* __restrict__ gw,
              const float* __restrict__ bew,  const float* __restrict__ muw,
              const float* __restrict__ varw,
              const float* __restrict__ x,
              const u8* __restrict__ o20, const u8* __restrict__ o21,
              float* __restrict__ outF)
{
    __shared__ __align__(16) char smem[49152];       // 2 x (A 8K + B 16K)
    const int tid = threadIdx.x;
    const int cpx = gridDim.x >> 3;                  // 64
    const int serial = (blockIdx.x & 7)*cpx + (blockIdx.x >> 3);
    const int nb = serial & 1, pbg = serial >> 1;
    const int half = pbg >> 7, pb = pbg & 127;
    const u8* Abits = half ? hh1 : hh0;
    const u8* o2g   = half ? o21 : o20;

    const int w = tid>>6, lane = tid&63, g = lane>>4, ln = lane&15;
    const int wm = w>>2, wn = w&3;                   // 2M x 4N, wave 64x64

    f32x4 acc[4][4];
    #pragma unroll
    for (int fm=0;fm<4;fm++)
        #pragma unroll
        for (int cb=0;cb<4;cb++) acc[fm][cb] = (f32x4)0.f;

    const u8* Bb = Bt + (i64)nb*64*16384;
    const int aRow = tid>>2, aGq = tid&3;
    const i64 aGrow = (i64)(aRow&3)*PH + pb*32 + (aRow>>2);

    {
        u32 b40 = *(const u32*)(Abits + aGrow*256);
        *(uint4*)(smem + swz(aRow, aGq*16)) = expandbits(b40 >> (8*aGq));
    }
    #pragma unroll
    for (int j=0;j<2;j++)
        gload16(Bb + (tid + j*512)*16, smem + 8192 + (tid + j*512)*16);
    __syncthreads();

    for (int ks=0; ks<64; ks++){
        char* cur = smem + (ks&1)*24576;
        char* nxt = smem + ((ks+1)&1)*24576;
        const bool pre = (ks+1 < 64);
        u32 b4n = 0;
        if (pre){
            b4n = *(const u32*)(Abits + aGrow*256 + (ks+1)*4);
            #pragma unroll
            for (int j=0;j<2;j++)
                gload16(Bb + (i64)(ks+1)*16384 + (tid+j*512)*16, nxt + 8192 + (tid+j*512)*16);
        }
        bf16x8 bfr[4], af[4];
        #pragma unroll
        for (int cb=0;cb<4;cb++)
            bfr[cb] = *(const bf16x8*)(cur + 8192 + g*4096 + (wn*64 + cb*16 + ln)*16);
        #pragma unroll
        for (int fm=0;fm<4;fm++)
            af[fm] = *(const bf16x8*)(cur + swz(wm*64 + fm*16 + ln, g*16));
        __builtin_amdgcn_s_setprio(1);
        #pragma unroll
        for (int fm=0;fm<4;fm++)
            #pragma unroll
            for (int cb=0;cb<4;cb++)
                acc[fm][cb] = MFMA(af[fm], bfr[cb], acc[fm][cb]);
        __builtin_amdgcn_s_setprio(0);
        if (pre)
            *(uint4*)(nxt + swz(aRow, aGq*16)) = expandbits(b4n >> (8*aGq));
        __syncthreads();
    }

    #pragma unroll
    for (int cb=0; cb<4; cb++){
        const int c = nb*256 + wn*64 + cb*16 + ln;
        const float gs  = gw[c] / sqrtf(varw[c] + BNEPS);
        const float bf_ = bias[c], muf = muw[c], bef = bew[c];
        #pragma unroll
        for (int fm=0; fm<4; fm++){
            const int prow = pb*32 + wm*16 + fm*4 + g;
            float v = 0.f;
            #pragma unroll
            for (int t=0; t<TT; t++){
                float y = acc[fm][cb][t] + bf_;
                float z = (y - muf) * gs + bef;
                v = v + (z - v) * 0.5f;
                float s = ((v - 1.0f) >= 0.f) ? 1.f : 0.f;
                i64 lrow = (i64)t*PH + prow;
                i64 grow = (i64)t*8192 + half*PH + prow;
                float xv = x[grow*512 + c];
                float o2v = (float)o2g[lrow*512 + c];
                outF[grow*512 + c] = (xv + o2v) + s;
                v = v * (1.f - s);
            }
        }
    }
}

// ---------------- p stage (r11 version, reverted): spikes x W GEMM + BN + LIF
//                  -> o2 (global) + f1 A-images (x+o2 split)
__global__ __launch_bounds__(256)
void gemm_p(const u8* __restrict__ Au8, const u16* __restrict__ WT,
            const float* __restrict__ bias, const float* __restrict__ gw,
            const float* __restrict__ bew,  const float* __restrict__ muw,
            const float* __restrict__ varw,
            const float* __restrict__ x, u8* __restrict__ o2g,
            u8* __restrict__ At, int pairBase)
{
    __shared__ __align__(16) char smem[16384];
    char* smA = smem;
    char* smB = smem + 8192;
    const int tid = threadIdx.x;
    const int nbp = blockIdx.x, pbp = blockIdx.y;
    const int c0 = nbp*128, pair0 = pbp*32;
    const int w = tid>>6, l = tid&63, g = l>>4, ln = l&15;
    const int wm = w>>1, wn = w&1;

    f32x4 acc[TT][4];
    #pragma unroll
    for (int t=0;t<TT;t++)
        #pragma unroll
        for (int cf=0;cf<4;cf++) acc[t][cf] = (f32x4)0.f;

    for (int k0 = 0; k0 < 512; k0 += 32){
        __syncthreads();
        {
            const int row = tid>>1, half = tid&1;
            const int t = row>>5, pp = row&31;
            const i64 grow = (i64)t*PH + pair0 + pp;
            uint4 ob = *(const uint4*)(Au8 + grow*512 + k0 + half*16);
            const u8* pbb = (const u8*)&ob;
            *(uint4*)(smA + swz(row, half*32))    = expand8(pbb);
            *(uint4*)(smA + swz(row, half*32+16)) = expand8(pbb+8);
        }
        #pragma unroll
        for (int j=0;j<2;j++){
            int cid = tid + j*256;
            int col = cid>>2, c = cid&3;
            uint4 d = *(const uint4*)(WT + (i64)(c0+col)*512 + k0 + c*8);
            *(uint4*)(smB + swz(col, c*16)) = d;
        }
        __syncthreads();
        bf16x8 bfr[4];
        #pragma unroll
        for (int cf=0;cf<4;cf++)
            bfr[cf] = *(const bf16x8*)(smB + swz(wn*64 + cf*16 + ln, g*16));
        #pragma unroll
        for (int t=0;t<TT;t++){
            bf16x8 afr = *(const bf16x8*)(smA + swz(t*32 + wm*16 + ln, g*16));
            #pragma unroll
            for (int cf=0;cf<4;cf++)
                acc[t][cf] = MFMA(afr, bfr[cf], acc[t][cf]);
        }
    }

    __syncthreads();
    u8* tile = (u8*)smem;
    #pragma unroll
    for (int cf=0;cf<4;cf++){
        const int c = c0 + wn*64 + cf*16 + ln;
        const float gs  = gw[c] / sqrtf(varw[c] + BNEPS);
        const float bf_ = bias[c], muf = muw[c], bef = bew[c];
        #pragma unroll
        for (int r=0;r<4;r++){
            const int rl = wm*16 + g*4 + r;
            float v = 0.f;
            #pragma unroll
            for (int t=0;t<TT;t++){
                float y = acc[t][cf][r] + bf_;
                float z = (y - muf) * gs + bef;
                v = v + (z - v) * 0.5f;
                float s = ((v - 1.0f) >= 0.f) ? 1.f : 0.f;
                tile[t*4096 + rl*128 + (wn*64 + cf*16 + ln)] = (u8)s;
                v = v * (1.f - s);
            }
        }
    }
    __syncthreads();

    const int pbImg = pbp>>1, rOff = (pbp&1)*128;
    #pragma unroll
    for (int it=0; it<8; it++){
        int task = tid + it*256;
        int kq = task>>9, rem = task&511, gq = rem>>7, rowL = rem&127;
        int rl = rowL>>2, t = rowL&3;
        int ksAbs = nbp*4 + kq;
        int cL = kq*32 + gq*8;
        uint2 ob = *(const uint2*)(tile + t*4096 + rl*128 + cL);
        const u8* pbb = (const u8*)&ob;
        i64 grow = (i64)t*8192 + pairBase + pair0 + rl;
        const float* src = x + grow*512 + ksAbs*32 + gq*8;
        float4 f0 = *(const float4*)src, f1v = *(const float4*)(src+4);
        float vv[8] = {f0.x,f0.y,f0.z,f0.w,f1v.x,f1v.y,f1v.z,f1v.w};
        #pragma unroll
        for (int j=0;j<8;j++) vv[j] = vv[j] + (float)pbb[j];
        u16 h[8], m[8];
        #pragma unroll
        for (int j=0;j<8;j++) split2(vv[j], h[j], m[j]);
        u8* img = At + ((i64)pbImg*KSW + ksAbs)*32768;
        int off = gq*4096 + (rOff + rowL)*16;
        *(ushort4*)(img + off)           = make_ushort4(h[0],h[1],h[2],h[3]);
        *(ushort4*)(img + off + 8)       = make_ushort4(h[4],h[5],h[6],h[7]);
        *(ushort4*)(img + 16384 + off)   = make_ushort4(m[0],m[1],m[2],m[3]);
        *(ushort4*)(img + 16384 + off+8) = make_ushort4(m[4],m[5],m[6],m[7]);
        *(uint2*)(o2g + ((i64)t*PH + pair0 + rl)*512 + ksAbs*32 + gq*8) = ob;
    }
}

// ---------------- spiking attention + attn-LIF (v_th=0.5), qkv packed stride 1536
__global__ __launch_bounds__(256)
void attn_lif_kernel(const u8* __restrict__ qkv, u8* __restrict__ os)
{
    __shared__ __align__(16) char smem[49152];
    char* Kl = smem;
    char* VT = smem + 16384;
    char* AT = smem + 32768;

    const int tid = threadIdx.x;
    const int w = tid>>6, l = tid&63, g = l>>4, ln = l&15;
    const int h = blockIdx.y, b = blockIdx.z;
    const int n0 = blockIdx.x*64 + w*16;

    f32x4 vmem[4];
    #pragma unroll
    for (int cf=0;cf<4;cf++) vmem[cf] = (f32x4)0.f;

    for (int t=0;t<TT;t++){
        const i64 tb = ((i64)(t*16 + b)*256)*1536;
        const i64 ob = ((i64)(t*16 + b)*256)*512 + h*64;
        bf16x8 qf[2];
        #pragma unroll
        for (int ksl=0;ksl<2;ksl++){
            uint2 qv = *(const uint2*)(qkv + tb + (i64)(n0+ln)*1536 + h*64 + ksl*32 + g*8);
            const u8* pb = (const u8*)&qv;
            BF8 f;
            #pragma unroll
            for (int j=0;j<8;j++) f.u[j] = pb[j] ? 0x3F80 : 0;
            qf[ksl] = f.v;
        }
        f32x4 oacc[4];
        #pragma unroll
        for (int cf=0;cf<4;cf++) oacc[cf] = (f32x4)0.f;

        for (int mh=0; mh<2; mh++){
            __syncthreads();
            {
                const int lm = tid>>1, seg = tid&1;
                const u8* src = qkv + tb + (i64)(mh*128+lm)*1536 + 512 + h*64 + seg*32;
                uint4 a = *(const uint4*)(src), c = *(const uint4*)(src+16);
                const u8* pa = (const u8*)&a; const u8* pc = (const u8*)&c;
                #pragma unroll
                for (int q=0;q<4;q++){
                    *(ushort4*)(Kl + swzK(lm, seg*64 + q*8)) =
                        make_ushort4(pa[q*4]?0x3F80:0, pa[q*4+1]?0x3F80:0, pa[q*4+2]?0x3F80:0, pa[q*4+3]?0x3F80:0);
                    *(ushort4*)(Kl + swzK(lm, seg*64 + 32 + q*8)) =
                        make_ushort4(pc[q*4]?0x3F80:0, pc[q*4+1]?0x3F80:0, pc[q*4+2]?0x3F80:0, pc[q*4+3]?0x3F80:0);
                }
            }
            {
                const int lm = tid>>1, seg = tid&1;
                const u8* src = qkv + tb + (i64)(mh*128+lm)*1536 + 1024 + h*64 + seg*32;
                uint4 a = *(const uint4*)(src), c = *(const uint4*)(src+16);
                const u8* pa = (const u8*)&a; const u8* pc = (const u8*)&c;
                #pragma unroll
                for (int j=0;j<16;j++){
                    *(u16*)(VT + swzV(seg*32 + j,      lm*2)) = pa[j] ? 0x3F80 : 0;
                    *(u16*)(VT + swzV(seg*32 + 16 + j, lm*2)) = pc[j] ? 0x3F80 : 0;
                }
            }
            __syncthreads();
            #pragma unroll
            for (int rf=0;rf<8;rf++){
                f32x4 s = (f32x4)0.f;
                #pragma unroll
                for (int ksl=0;ksl<2;ksl++){
                    bf16x8 kf = *(const bf16x8*)(Kl + swzK(rf*16+ln, ksl*64 + g*16));
                    s = MFMA(kf, qf[ksl], s);
                }
                ushort4 pk = make_ushort4(f2bf_rne(s[0]*0.125f), f2bf_rne(s[1]*0.125f),
                                          f2bf_rne(s[2]*0.125f), f2bf_rne(s[3]*0.125f));
                *(ushort4*)(AT + swzV(w*16+ln, rf*32 + g*8)) = pk;
            }
            #pragma unroll
            for (int ms=0;ms<4;ms++){
                bf16x8 af = *(const bf16x8*)(AT + swzV(w*16+ln, ms*64 + g*16));
                #pragma unroll
                for (int cf=0;cf<4;cf++){
                    bf16x8 vf = *(const bf16x8*)(VT + swzV(cf*16+ln, ms*64 + g*16));
                    oacc[cf] = MFMA(af, vf, oacc[cf]);
                }
            }
        }
        #pragma unroll
        for (int cf=0;cf<4;cf++)
            #pragma unroll
            for (int r=0;r<4;r++){
                float v = vmem[cf][r];
                v = v + (oacc[cf][r] - v) * 0.5f;
                float s = ((v - 0.5f) >= 0.f) ? 1.f : 0.f;
                os[ob + (i64)(n0 + g*4 + r)*512 + cf*16 + ln] = (u8)s;
                vmem[cf][r] = v * (1.f - s);
            }
    }
}

extern "C" void kernel_launch(void* const* d_in, const int* in_sizes, int n_in,
                              void* d_out, int out_size, void* d_ws, size_t ws_size,
                              hipStream_t stream)
{
    (void)in_sizes; (void)n_in; (void)out_size; (void)ws_size;
    const float* x = (const float*)d_in[0];
    #define GETP(i) ((const float*)d_in[i])

    char* ws = (char*)d_ws;
    u8*  Bqkv = (u8*)(ws + 0);               // 12*16*8192 = 1,572,864
    u8*  Bf1  = (u8*)(ws + 1572864);         // 16*16*8192 = 2,097,152
    u8*  Bf2  = (u8*)(ws + 3670016);         //  2*64*16384 = 2,097,152
    u16* WTp  = (u16*)(ws + 5767168);        //  524,288
    u8*  At   = (u8*)(ws + 6291456);         // 64*16*32768 = 33,554,432
    u8*  qkv  = (u8*)(ws + 39845888);        // 25,165,824
    u8*  os_  = (u8*)(ws + 65011712);        //  8,388,608
    u8*  o2h[2] = { (u8*)(ws + 73400320), (u8*)(ws + 81788928) };   // 8,388,608 each
    u8*  hhb[2] = { (u8*)(ws + 90177536), (u8*)(ws + 94371840) };   // 4,194,304 each -> ends 98,566,144

    hipFuncSetAttribute((const void*)gemm8<false>, hipFuncAttributeMaxDynamicSharedMemorySize, 81920);
    hipFuncSetAttribute((const void*)gemm8<true>,  hipFuncAttributeMaxDynamicSharedMemorySize, 81920);

    dim3 blk(256,1,1);
    // W prep: qkv/f1 use 128-col images; f2 keeps 256-col
    wsplit_rne<<<dim3(16,4), blk,0,stream>>>(GETP(1),  Bqkv, 512, 0, 16, 128);
    wsplit_rne<<<dim3(16,4), blk,0,stream>>>(GETP(7),  Bqkv, 512, 4, 16, 128);
    wsplit_rne<<<dim3(16,4), blk,0,stream>>>(GETP(13), Bqkv, 512, 8, 16, 128);
    wsplit_rne<<<dim3(16,16),blk,0,stream>>>(GETP(25), Bf1, 2048, 0, 16, 128);
    wsplit_rne<<<dim3(64,2), blk,0,stream>>>(GETP(31), Bf2,  512, 0, 64, 256);
    wsplit_old<<<dim3(8,8),  blk,0,stream>>>(GETP(19), WTp,  512, 512);

    for (int hb = 0; hb < 2; hb++){
        const int pb = hb * PH;
        asplitT<<<dim3(64,16),blk,0,stream>>>(x, At, pb);
        // fused q/k/v (N=1536, NB=12, grid 768)
        gemm8<false><<<dim3(768),dim3(512),81920,stream>>>(At, Bqkv,
            GETP(2),GETP(8),GETP(14),  GETP(3),GETP(9),GETP(15),
            GETP(4),GETP(10),GETP(16), GETP(5),GETP(11),GETP(17),
            GETP(6),GETP(12),GETP(18), qkv, 12, 1536, 511);
        attn_lif_kernel<<<dim3(4,8,16),blk,0,stream>>>(qkv, os_);
        // p stage + fused o2/f1-image production
        gemm_p<<<dim3(4,128),blk,0,stream>>>(os_, WTp,
            GETP(20),GETP(21),GETP(22),GETP(23),GETP(24), x, o2h[hb], At, pb);
        // f1 (N=2048, NB=16, grid 1024, bitpacked out)
        gemm8<true><<<dim3(1024),dim3(512),81920,stream>>>(At, Bf1,
            GETP(26),GETP(26),GETP(26), GETP(27),GETP(27),GETP(27),
            GETP(28),GETP(28),GETP(28), GETP(29),GETP(29),GETP(29),
            GETP(30),GETP(30),GETP(30), hhb[hb], 16, 2048, 2047);
    }
    // f2 v3: both halves, grid 512, T14 staging, fused final add -> d_out
    gemm8_f2<<<dim3(512),dim3(512),0,stream>>>(hhb[0], hhb[1], Bf2,
        GETP(32),GETP(33),GETP(34),GETP(35),GETP(36), x, o2h[0], o2h[1], (float*)d_out);
}

// Round 14
// 499.889 us; speedup vs baseline: 1.0913x; 1.0135x over previous
//
#include <hip/hip_runtime.h>

typedef unsigned char u8;
typedef unsigned short u16;
typedef unsigned int u32;
typedef unsigned long long u64;
typedef long long i64;

#define TT 4
#define PH 4096             // pairs per half
#define KSW 16              // K/32 images for K=512
#define BNEPS 1e-5f

typedef __attribute__((ext_vector_type(8))) __bf16 bf16x8;
typedef __attribute__((ext_vector_type(4))) float f32x4;

__device__ __forceinline__ float bf2f(u16 b){ return __uint_as_float(((u32)b)<<16); }
__device__ __forceinline__ u16 f2bf_rne(float f){ u32 u = __float_as_uint(f); return (u16)((u + 0x7FFFu + ((u>>16)&1u))>>16); }
__device__ __forceinline__ u16 f2bf_tr(float f){ return (u16)(__float_as_uint(f)>>16); }

__device__ __forceinline__ void split2(float v, u16& h, u16& m){
    h = f2bf_tr(v); m = f2bf_tr(v - bf2f(h));
}

__device__ __forceinline__ f32x4 MFMA(bf16x8 a, bf16x8 b, f32x4 c){
    return __builtin_amdgcn_mfma_f32_16x16x32_bf16(a, b, c, 0, 0, 0);
}

union BF8 { u16 u[8]; bf16x8 v; };

__device__ __forceinline__ void gload16(const void* g, void* l){
    __builtin_amdgcn_global_load_lds(
        (const __attribute__((address_space(1))) unsigned int*)g,
        (__attribute__((address_space(3))) unsigned int*)l, 16, 0, 0);
}

// reg-staged kernels' swizzles (validated r3-r13)
__device__ __forceinline__ int swz(int row, int off){ return row*64 + (off ^ (((row>>1)&3)<<4)); }
__device__ __forceinline__ int swzK(int row, int off){ return row*128 + (off ^ ((row&7)<<4)); }
__device__ __forceinline__ int swzV(int row, int off){ return row*256 + (off ^ ((row&7)<<4)); }

__device__ __forceinline__ uint4 expand8(const u8* pb){
    u32 w0 = (pb[0]?0x3F80u:0u) | ((pb[1]?0x3F80u:0u)<<16);
    u32 w1 = (pb[2]?0x3F80u:0u) | ((pb[3]?0x3F80u:0u)<<16);
    u32 w2 = (pb[4]?0x3F80u:0u) | ((pb[5]?0x3F80u:0u)<<16);
    u32 w3 = (pb[6]?0x3F80u:0u) | ((pb[7]?0x3F80u:0u)<<16);
    return make_uint4(w0,w1,w2,w3);
}
__device__ __forceinline__ uint4 expandbits(u32 bits){
    u32 w0 = ((bits>>0)&1?0x3F80u:0u) | ((bits>>1)&1?0x3F800000u:0u);
    u32 w1 = ((bits>>2)&1?0x3F80u:0u) | ((bits>>3)&1?0x3F800000u:0u);
    u32 w2 = ((bits>>4)&1?0x3F80u:0u) | ((bits>>5)&1?0x3F800000u:0u);
    u32 w3 = ((bits>>6)&1?0x3F80u:0u) | ((bits>>7)&1?0x3F800000u:0u);
    return make_uint4(w0,w1,w2,w3);
}

// ---------------- W -> CB-col 1-plane RNE images
__global__ __launch_bounds__(256)
void wsplit_rne(const float* __restrict__ W, u8* __restrict__ out, int NC, int nbOff, int ksn, int CB)
{
    const int ks = blockIdx.x, nbl = blockIdx.y;
    const int c0 = nbl*CB;
    u8* img = out + ((i64)(nbOff+nbl)*ksn + ks)*(i64)(CB*64);
    const int iters = CB >> 6;
    for (int it=0; it<iters; it++){
        int task = threadIdx.x + it*256;
        int col = task>>2, gq = task&3;
        float v[8];
        #pragma unroll
        for (int j=0;j<8;j++) v[j] = W[(i64)(ks*32 + gq*8 + j)*NC + c0 + col];
        u16 h[8];
        #pragma unroll
        for (int j=0;j<8;j++) h[j] = f2bf_rne(v[j]);
        int off = gq*(CB*16) + col*16;
        *(ushort4*)(img + off)     = make_ushort4(h[0],h[1],h[2],h[3]);
        *(ushort4*)(img + off + 8) = make_ushort4(h[4],h[5],h[6],h[7]);
    }
}

// ---------------- W -> RNE bf16 [NC][K] (for p reg-staged GEMM)
__global__ __launch_bounds__(256)
void wsplit_old(const float* __restrict__ W, u16* __restrict__ out, int K, int NC)
{
    __shared__ float tile[64][65];
    const int k0 = blockIdx.x*64, c0 = blockIdx.y*64;
    const int tid = threadIdx.x;
    #pragma unroll
    for (int j=0;j<16;j++){
        int el = tid + j*256; int r = el>>6, c = el&63;
        tile[r][c] = W[(i64)(k0+r)*NC + c0 + c];
    }
    __syncthreads();
    #pragma unroll
    for (int j=0;j<16;j++){
        int el = tid + j*256; int c = el>>6, k = el&63;
        out[(i64)(c0+c)*K + k0 + k] = f2bf_rne(tile[k][c]);
    }
}

// ---------------- x -> A images: img(pb,ks)[pl][g][row 0..255][16B], row = pair*4 + t, 32KB
__global__ __launch_bounds__(256)
void asplitT(const float* __restrict__ x, u8* __restrict__ At, int pairBase)
{
    const int pb = blockIdx.x, ks = blockIdx.y;
    u8* img = At + ((i64)pb*KSW + ks)*32768;
    #pragma unroll
    for (int it=0; it<4; it++){
        int task = threadIdx.x + it*256;
        int row = task>>2, gq = task&3;
        int pair = row>>2, t = row&3;
        i64 grow = (i64)t*8192 + pairBase + pb*64 + pair;
        const float* src = x + grow*512 + ks*32 + gq*8;
        float4 f0 = *(const float4*)src, f1v = *(const float4*)(src+4);
        float vv[8] = {f0.x,f0.y,f0.z,f0.w,f1v.x,f1v.y,f1v.z,f1v.w};
        u16 h[8], m[8];
        #pragma unroll
        for (int j=0;j<8;j++) split2(vv[j], h[j], m[j]);
        int off = gq*4096 + row*16;
        *(ushort4*)(img + off)           = make_ushort4(h[0],h[1],h[2],h[3]);
        *(ushort4*)(img + off + 8)       = make_ushort4(h[4],h[5],h[6],h[7]);
        *(ushort4*)(img + 16384 + off)   = make_ushort4(m[0],m[1],m[2],m[3]);
        *(ushort4*)(img + 16384 + off+8) = make_ushort4(m[4],m[5],m[6],m[7]);
    }
}

// ---------------- gemm8 v3: BM=256 x BN=128, dbuf 80KB -> 2 blocks/CU, 8 waves 4Mx2N.
// LDS-staged coalesced u8 epilogue for the non-bitout (qkv) path.
template<bool BITOUT>
__global__ __launch_bounds__(512,4)
void gemm8(const u8* __restrict__ At, const u8* __restrict__ Bt,
           const float* __restrict__ b0, const float* __restrict__ b1, const float* __restrict__ b2,
           const float* __restrict__ g0, const float* __restrict__ g1, const float* __restrict__ g2,
           const float* __restrict__ e0, const float* __restrict__ e1, const float* __restrict__ e2,
           const float* __restrict__ u0, const float* __restrict__ u1, const float* __restrict__ u2,
           const float* __restrict__ v0, const float* __restrict__ v1, const float* __restrict__ v2,
           u8* __restrict__ outp, int NB, int NCT, int cmask)
{
    extern __shared__ __align__(16) char smem[];     // 81920: 2 x (A 32K + B 8K)
    const int tid = threadIdx.x;
    const int cpx = gridDim.x >> 3;
    const int serial = (blockIdx.x & 7)*cpx + (blockIdx.x >> 3);
    const int pb = serial / NB, nb = serial % NB;

    const int w = tid>>6, lane = tid&63, g = lane>>4, ln = lane&15;
    const int wm = w>>1, wn = w&1;                   // 4M x 2N, wave 64x64

    f32x4 acc[4][4];
    #pragma unroll
    for (int fm=0;fm<4;fm++)
        #pragma unroll
        for (int cb=0;cb<4;cb++) acc[fm][cb] = (f32x4)0.f;

    const u8* Ab = At + (i64)pb*KSW*32768;
    const u8* Bb = Bt + (i64)nb*KSW*8192;

    #pragma unroll
    for (int j=0;j<4;j++)
        gload16(Ab + j*8192 + tid*16, smem + j*8192 + tid*16);
    gload16(Bb + tid*16, smem + 32768 + tid*16);
    __syncthreads();

    for (int ks=0; ks<KSW; ks++){
        char* cur = smem + (ks&1)*40960;
        char* nxt = smem + ((ks+1)&1)*40960;
        if (ks+1 < KSW){
            const u8* Ai = Ab + (i64)(ks+1)*32768;
            #pragma unroll
            for (int j=0;j<4;j++) gload16(Ai + j*8192 + tid*16, nxt + j*8192 + tid*16);
            gload16(Bb + (i64)(ks+1)*8192 + tid*16, nxt + 32768 + tid*16);
        }
        bf16x8 bfr[4];
        #pragma unroll
        for (int cb=0;cb<4;cb++){
            int col = wn*64 + cb*16 + ln;
            bfr[cb] = *(const bf16x8*)(cur + 32768 + g*2048 + col*16);
        }
        __builtin_amdgcn_s_setprio(1);
        #pragma unroll
        for (int fm=0; fm<4; fm++){
            int row = wm*64 + fm*16 + ln;
            bf16x8 a0 = *(const bf16x8*)(cur + g*4096 + row*16);
            bf16x8 a1 = *(const bf16x8*)(cur + 16384 + g*4096 + row*16);
            #pragma unroll
            for (int cb=0;cb<4;cb++){
                f32x4 x4 = acc[fm][cb];
                x4 = MFMA(a0, bfr[cb], x4);
                x4 = MFMA(a1, bfr[cb], x4);
                acc[fm][cb] = x4;
            }
        }
        __builtin_amdgcn_s_setprio(0);
        __syncthreads();
    }

    if (BITOUT){
        #pragma unroll
        for (int cb=0; cb<4; cb++){
            const int c = nb*128 + wn*64 + cb*16 + ln;
            const float gs  = g0[c & cmask] / sqrtf(v0[c & cmask] + BNEPS);
            const float bf_ = b0[c & cmask], muf = u0[c & cmask], bef = e0[c & cmask];
            #pragma unroll
            for (int fm=0; fm<4; fm++){
                const int prow = pb*64 + wm*16 + fm*4 + g;
                float v = 0.f;
                #pragma unroll
                for (int t=0; t<TT; t++){
                    float y = acc[fm][cb][t] + bf_;
                    float z = (y - muf) * gs + bef;
                    v = v + (z - v) * 0.5f;
                    float s = ((v - 1.0f) >= 0.f) ? 1.f : 0.f;
                    u64 bal = __ballot(s != 0.f);
                    if (ln == 0)
                        *(u16*)(outp + (i64)(t*PH + prow)*(NCT>>3) + ((nb*128 + wn*64 + cb*16)>>3)) = (u16)(bal >> (g*16));
                    v = v * (1.f - s);
                }
            }
        }
    } else {
        // LDS-staged coalesced epilogue: tile [t][64 rows][128 c] u8 = 32KB
        u8* tile = (u8*)smem;
        #pragma unroll
        for (int cb=0; cb<4; cb++){
            const int c = nb*128 + wn*64 + cb*16 + ln;
            int which = c >> 9; if (which > 2) which = 2;
            const float* bp = which==0?b0:(which==1?b1:b2);
            const float* gp = which==0?g0:(which==1?g1:g2);
            const float* ep = which==0?e0:(which==1?e1:e2);
            const float* up = which==0?u0:(which==1?u1:u2);
            const float* vp = which==0?v0:(which==1?v1:v2);
            const int ci = c & cmask;
            const float gs  = gp[ci] / sqrtf(vp[ci] + BNEPS);
            const float bf_ = bp[ci], muf = up[ci], bef = ep[ci];
            #pragma unroll
            for (int fm=0; fm<4; fm++){
                const int rowL = wm*16 + fm*4 + g;
                float v = 0.f;
                #pragma unroll
                for (int t=0; t<TT; t++){
                    float y = acc[fm][cb][t] + bf_;
                    float z = (y - muf) * gs + bef;
                    v = v + (z - v) * 0.5f;
                    float s = ((v - 1.0f) >= 0.f) ? 1.f : 0.f;
                    tile[t*8192 + rowL*128 + (wn*64 + cb*16 + ln)] = (u8)s;
                    v = v * (1.f - s);
                }
            }
        }
        __syncthreads();
        #pragma unroll
        for (int it=0; it<4; it++){
            int task = tid + it*512;
            int t = task>>9, row = (task>>3)&63, seg = task&7;
            uint4 d = *(const uint4*)(tile + t*8192 + row*128 + seg*16);
            *(uint4*)(outp + (i64)(t*PH + pb*64 + row)*NCT + nb*128 + seg*16) = d;
        }
    }
}

// ---------------- f2 v4: BM=128 x BN=256, K=2048, grid 512, T14 staging,
// LDS-transpose coalesced epilogue (float4 x/out, u32 o2).
__global__ __launch_bounds__(512,4)
void gemm8_f2(const u8* __restrict__ hh0, const u8* __restrict__ hh1,
              const u8* __restrict__ Bt,
              const float* __restrict__ bias, const float* __restrict__ gw,
              const float* __restrict__ bew,  const float* __restrict__ muw,
              const float* __restrict__ varw,
              const float* __restrict__ x,
              const u8* __restrict__ o20, const u8* __restrict__ o21,
              float* __restrict__ outF)
{
    __shared__ __align__(16) char smem[49152];       // 2 x (A 8K + B 16K); epilogue reuses 34KB
    const int tid = threadIdx.x;
    const int cpx = gridDim.x >> 3;                  // 64
    const int serial = (blockIdx.x & 7)*cpx + (blockIdx.x >> 3);
    const int nb = serial & 1, pbg = serial >> 1;
    const int half = pbg >> 7, pb = pbg & 127;
    const u8* Abits = half ? hh1 : hh0;
    const u8* o2g   = half ? o21 : o20;

    const int w = tid>>6, lane = tid&63, g = lane>>4, ln = lane&15;
    const int wm = w>>2, wn = w&3;                   // 2M x 4N, wave 64x64

    f32x4 acc[4][4];
    #pragma unroll
    for (int fm=0;fm<4;fm++)
        #pragma unroll
        for (int cb=0;cb<4;cb++) acc[fm][cb] = (f32x4)0.f;

    const u8* Bb = Bt + (i64)nb*64*16384;
    const int aRow = tid>>2, aGq = tid&3;
    const i64 aGrow = (i64)(aRow&3)*PH + pb*32 + (aRow>>2);

    {
        u32 b40 = *(const u32*)(Abits + aGrow*256);
        *(uint4*)(smem + swz(aRow, aGq*16)) = expandbits(b40 >> (8*aGq));
    }
    #pragma unroll
    for (int j=0;j<2;j++)
        gload16(Bb + (tid + j*512)*16, smem + 8192 + (tid + j*512)*16);
    __syncthreads();

    for (int ks=0; ks<64; ks++){
        char* cur = smem + (ks&1)*24576;
        char* nxt = smem + ((ks+1)&1)*24576;
        const bool pre = (ks+1 < 64);
        u32 b4n = 0;
        if (pre){
            b4n = *(const u32*)(Abits + aGrow*256 + (ks+1)*4);
            #pragma unroll
            for (int j=0;j<2;j++)
                gload16(Bb + (i64)(ks+1)*16384 + (tid+j*512)*16, nxt + 8192 + (tid+j*512)*16);
        }
        bf16x8 bfr[4], af[4];
        #pragma unroll
        for (int cb=0;cb<4;cb++)
            bfr[cb] = *(const bf16x8*)(cur + 8192 + g*4096 + (wn*64 + cb*16 + ln)*16);
        #pragma unroll
        for (int fm=0;fm<4;fm++)
            af[fm] = *(const bf16x8*)(cur + swz(wm*64 + fm*16 + ln, g*16));
        __builtin_amdgcn_s_setprio(1);
        #pragma unroll
        for (int fm=0;fm<4;fm++)
            #pragma unroll
            for (int cb=0;cb<4;cb++)
                acc[fm][cb] = MFMA(af[fm], bfr[cb], acc[fm][cb]);
        __builtin_amdgcn_s_setprio(0);
        if (pre)
            *(uint4*)(nxt + swz(aRow, aGq*16)) = expandbits(b4n >> (8*aGq));
        __syncthreads();
    }

    // epilogue: BN + LIF in regs; per-t LDS transpose; coalesced float4 combine+store
    float gsA[4], bfA[4], muA[4], beA[4];
    #pragma unroll
    for (int cb=0;cb<4;cb++){
        const int c = nb*256 + wn*64 + cb*16 + ln;
        gsA[cb] = gw[c] / sqrtf(varw[c] + BNEPS);
        bfA[cb] = bias[c]; muA[cb] = muw[c]; beA[cb] = bew[c];
    }
    float vst[4][4];
    #pragma unroll
    for (int fm=0;fm<4;fm++)
        #pragma unroll
        for (int cb=0;cb<4;cb++) vst[fm][cb] = 0.f;

    float* ft = (float*)smem;                        // [32 rows][stride 264 f32] = 33792 B
    for (int t=0; t<TT; t++){
        __syncthreads();                             // prev t reads done / LDS free
        #pragma unroll
        for (int cb=0;cb<4;cb++)
            #pragma unroll
            for (int fm=0;fm<4;fm++){
                const int rowL = wm*16 + fm*4 + g;
                float y = acc[fm][cb][t] + bfA[cb];
                float z = (y - muA[cb]) * gsA[cb] + beA[cb];
                float v = vst[fm][cb];
                v = v + (z - v) * 0.5f;
                float s = ((v - 1.0f) >= 0.f) ? 1.f : 0.f;
                ft[rowL*264 + wn*64 + cb*16 + ln] = s;
                vst[fm][cb] = v * (1.f - s);
            }
        __syncthreads();
        #pragma unroll
        for (int it=0; it<4; it++){
            int task = tid + it*512;                 // 2048 tasks = 32 rows x 64 segs
            int rowL = task>>6, seg = task&63;
            float4 sv = *(const float4*)(ft + rowL*264 + seg*4);
            i64 grow = (i64)t*8192 + half*PH + pb*32 + rowL;
            i64 lrow = (i64)t*PH + pb*32 + rowL;
            const int cg = nb*256 + seg*4;
            float4 xv = *(const float4*)(x + grow*512 + cg);
            u32 o4 = *(const u32*)(o2g + lrow*512 + cg);
            float4 r;
            r.x = (xv.x + (float)( o4      &255u)) + sv.x;
            r.y = (xv.y + (float)((o4>> 8) &255u)) + sv.y;
            r.z = (xv.z + (float)((o4>>16) &255u)) + sv.z;
            r.w = (xv.w + (float)((o4>>24) &255u)) + sv.w;
            *(float4*)(outF + grow*512 + cg) = r;
        }
    }
}

// ---------------- p stage (r11 version): spikes x W GEMM + BN + LIF
//                  -> o2 (global) + f1 A-images (x+o2 split)
__global__ __launch_bounds__(256)
void gemm_p(const u8* __restrict__ Au8, const u16* __restrict__ WT,
            const float* __restrict__ bias, const float* __restrict__ gw,
            const float* __restrict__ bew,  const float* __restrict__ muw,
            const float* __restrict__ varw,
            const float* __restrict__ x, u8* __restrict__ o2g,
            u8* __restrict__ At, int pairBase)
{
    __shared__ __align__(16) char smem[16384];
    char* smA = smem;
    char* smB = smem + 8192;
    const int tid = threadIdx.x;
    const int nbp = blockIdx.x, pbp = blockIdx.y;
    const int c0 = nbp*128, pair0 = pbp*32;
    const int w = tid>>6, l = tid&63, g = l>>4, ln = l&15;
    const int wm = w>>1, wn = w&1;

    f32x4 acc[TT][4];
    #pragma unroll
    for (int t=0;t<TT;t++)
        #pragma unroll
        for (int cf=0;cf<4;cf++) acc[t][cf] = (f32x4)0.f;

    for (int k0 = 0; k0 < 512; k0 += 32){
        __syncthreads();
        {
            const int row = tid>>1, half = tid&1;
            const int t = row>>5, pp = row&31;
            const i64 grow = (i64)t*PH + pair0 + pp;
            uint4 ob = *(const uint4*)(Au8 + grow*512 + k0 + half*16);
            const u8* pbb = (const u8*)&ob;
            *(uint4*)(smA + swz(row, half*32))    = expand8(pbb);
            *(uint4*)(smA + swz(row, half*32+16)) = expand8(pbb+8);
        }
        #pragma unroll
        for (int j=0;j<2;j++){
            int cid = tid + j*256;
            int col = cid>>2, c = cid&3;
            uint4 d = *(const uint4*)(WT + (i64)(c0+col)*512 + k0 + c*8);
            *(uint4*)(smB + swz(col, c*16)) = d;
        }
        __syncthreads();
        bf16x8 bfr[4];
        #pragma unroll
        for (int cf=0;cf<4;cf++)
            bfr[cf] = *(const bf16x8*)(smB + swz(wn*64 + cf*16 + ln, g*16));
        #pragma unroll
        for (int t=0;t<TT;t++){
            bf16x8 afr = *(const bf16x8*)(smA + swz(t*32 + wm*16 + ln, g*16));
            #pragma unroll
            for (int cf=0;cf<4;cf++)
                acc[t][cf] = MFMA(afr, bfr[cf], acc[t][cf]);
        }
    }

    __syncthreads();
    u8* tile = (u8*)smem;
    #pragma unroll
    for (int cf=0;cf<4;cf++){
        const int c = c0 + wn*64 + cf*16 + ln;
        const float gs  = gw[c] / sqrtf(varw[c] + BNEPS);
        const float bf_ = bias[c], muf = muw[c], bef = bew[c];
        #pragma unroll
        for (int r=0;r<4;r++){
            const int rl = wm*16 + g*4 + r;
            float v = 0.f;
            #pragma unroll
            for (int t=0;t<TT;t++){
                float y = acc[t][cf][r] + bf_;
                float z = (y - muf) * gs + bef;
                v = v + (z - v) * 0.5f;
                float s = ((v - 1.0f) >= 0.f) ? 1.f : 0.f;
                tile[t*4096 + rl*128 + (wn*64 + cf*16 + ln)] = (u8)s;
                v = v * (1.f - s);
            }
        }
    }
    __syncthreads();

    const int pbImg = pbp>>1, rOff = (pbp&1)*128;
    #pragma unroll
    for (int it=0; it<8; it++){
        int task = tid + it*256;
        int kq = task>>9, rem = task&511, gq = rem>>7, rowL = rem&127;
        int rl = rowL>>2, t = rowL&3;
        int ksAbs = nbp*4 + kq;
        int cL = kq*32 + gq*8;
        uint2 ob = *(const uint2*)(tile + t*4096 + rl*128 + cL);
        const u8* pbb = (const u8*)&ob;
        i64 grow = (i64)t*8192 + pairBase + pair0 + rl;
        const float* src = x + grow*512 + ksAbs*32 + gq*8;
        float4 f0 = *(const float4*)src, f1v = *(const float4*)(src+4);
        float vv[8] = {f0.x,f0.y,f0.z,f0.w,f1v.x,f1v.y,f1v.z,f1v.w};
        #pragma unroll
        for (int j=0;j<8;j++) vv[j] = vv[j] + (float)pbb[j];
        u16 h[8], m[8];
        #pragma unroll
        for (int j=0;j<8;j++) split2(vv[j], h[j], m[j]);
        u8* img = At + ((i64)pbImg*KSW + ksAbs)*32768;
        int off = gq*4096 + (rOff + rowL)*16;
        *(ushort4*)(img + off)           = make_ushort4(h[0],h[1],h[2],h[3]);
        *(ushort4*)(img + off + 8)       = make_ushort4(h[4],h[5],h[6],h[7]);
        *(ushort4*)(img + 16384 + off)   = make_ushort4(m[0],m[1],m[2],m[3]);
        *(ushort4*)(img + 16384 + off+8) = make_ushort4(m[4],m[5],m[6],m[7]);
        *(uint2*)(o2g + ((i64)t*PH + pair0 + rl)*512 + ksAbs*32 + gq*8) = ob;
    }
}

// ---------------- spiking attention + attn-LIF (v_th=0.5), qkv packed stride 1536
__global__ __launch_bounds__(256)
void attn_lif_kernel(const u8* __restrict__ qkv, u8* __restrict__ os)
{
    __shared__ __align__(16) char smem[49152];
    char* Kl = smem;
    char* VT = smem + 16384;
    char* AT = smem + 32768;

    const int tid = threadIdx.x;
    const int w = tid>>6, l = tid&63, g = l>>4, ln = l&15;
    const int h = blockIdx.y, b = blockIdx.z;
    const int n0 = blockIdx.x*64 + w*16;

    f32x4 vmem[4];
    #pragma unroll
    for (int cf=0;cf<4;cf++) vmem[cf] = (f32x4)0.f;

    for (int t=0;t<TT;t++){
        const i64 tb = ((i64)(t*16 + b)*256)*1536;
        const i64 ob = ((i64)(t*16 + b)*256)*512 + h*64;
        bf16x8 qf[2];
        #pragma unroll
        for (int ksl=0;ksl<2;ksl++){
            uint2 qv = *(const uint2*)(qkv + tb + (i64)(n0+ln)*1536 + h*64 + ksl*32 + g*8);
            const u8* pb = (const u8*)&qv;
            BF8 f;
            #pragma unroll
            for (int j=0;j<8;j++) f.u[j] = pb[j] ? 0x3F80 : 0;
            qf[ksl] = f.v;
        }
        f32x4 oacc[4];
        #pragma unroll
        for (int cf=0;cf<4;cf++) oacc[cf] = (f32x4)0.f;

        for (int mh=0; mh<2; mh++){
            __syncthreads();
            {
                const int lm = tid>>1, seg = tid&1;
                const u8* src = qkv + tb + (i64)(mh*128+lm)*1536 + 512 + h*64 + seg*32;
                uint4 a = *(const uint4*)(src), c = *(const uint4*)(src+16);
                const u8* pa = (const u8*)&a; const u8* pc = (const u8*)&c;
                #pragma unroll
                for (int q=0;q<4;q++){
                    *(ushort4*)(Kl + swzK(lm, seg*64 + q*8)) =
                        make_ushort4(pa[q*4]?0x3F80:0, pa[q*4+1]?0x3F80:0, pa[q*4+2]?0x3F80:0, pa[q*4+3]?0x3F80:0);
                    *(ushort4*)(Kl + swzK(lm, seg*64 + 32 + q*8)) =
                        make_ushort4(pc[q*4]?0x3F80:0, pc[q*4+1]?0x3F80:0, pc[q*4+2]?0x3F80:0, pc[q*4+3]?0x3F80:0);
                }
            }
            {
                const int lm = tid>>1, seg = tid&1;
                const u8* src = qkv + tb + (i64)(mh*128+lm)*1536 + 1024 + h*64 + seg*32;
                uint4 a = *(const uint4*)(src), c = *(const uint4*)(src+16);
                const u8* pa = (const u8*)&a; const u8* pc = (const u8*)&c;
                #pragma unroll
                for (int j=0;j<16;j++){
                    *(u16*)(VT + swzV(seg*32 + j,      lm*2)) = pa[j] ? 0x3F80 : 0;
                    *(u16*)(VT + swzV(seg*32 + 16 + j, lm*2)) = pc[j] ? 0x3F80 : 0;
                }
            }
            __syncthreads();
            #pragma unroll
            for (int rf=0;rf<8;rf++){
                f32x4 s = (f32x4)0.f;
                #pragma unroll
                for (int ksl=0;ksl<2;ksl++){
                    bf16x8 kf = *(const bf16x8*)(Kl + swzK(rf*16+ln, ksl*64 + g*16));
                    s = MFMA(kf, qf[ksl], s);
                }
                ushort4 pk = make_ushort4(f2bf_rne(s[0]*0.125f), f2bf_rne(s[1]*0.125f),
                                          f2bf_rne(s[2]*0.125f), f2bf_rne(s[3]*0.125f));
                *(ushort4*)(AT + swzV(w*16+ln, rf*32 + g*8)) = pk;
            }
            #pragma unroll
            for (int ms=0;ms<4;ms++){
                bf16x8 af = *(const bf16x8*)(AT + swzV(w*16+ln, ms*64 + g*16));
                #pragma unroll
                for (int cf=0;cf<4;cf++){
                    bf16x8 vf = *(const bf16x8*)(VT + swzV(cf*16+ln, ms*64 + g*16));
                    oacc[cf] = MFMA(af, vf, oacc[cf]);
                }
            }
        }
        #pragma unroll
        for (int cf=0;cf<4;cf++)
            #pragma unroll
            for (int r=0;r<4;r++){
                float v = vmem[cf][r];
                v = v + (oacc[cf][r] - v) * 0.5f;
                float s = ((v - 0.5f) >= 0.f) ? 1.f : 0.f;
                os[ob + (i64)(n0 + g*4 + r)*512 + cf*16 + ln] = (u8)s;
                vmem[cf][r] = v * (1.f - s);
            }
    }
}

extern "C" void kernel_launch(void* const* d_in, const int* in_sizes, int n_in,
                              void* d_out, int out_size, void* d_ws, size_t ws_size,
                              hipStream_t stream)
{
    (void)in_sizes; (void)n_in; (void)out_size; (void)ws_size;
    const float* x = (const float*)d_in[0];
    #define GETP(i) ((const float*)d_in[i])

    char* ws = (char*)d_ws;
    u8*  Bqkv = (u8*)(ws + 0);               // 12*16*8192 = 1,572,864
    u8*  Bf1  = (u8*)(ws + 1572864);         // 16*16*8192 = 2,097,152
    u8*  Bf2  = (u8*)(ws + 3670016);         //  2*64*16384 = 2,097,152
    u16* WTp  = (u16*)(ws + 5767168);        //  524,288
    u8*  At   = (u8*)(ws + 6291456);         // 64*16*32768 = 33,554,432
    u8*  qkv  = (u8*)(ws + 39845888);        // 25,165,824
    u8*  os_  = (u8*)(ws + 65011712);        //  8,388,608
    u8*  o2h[2] = { (u8*)(ws + 73400320), (u8*)(ws + 81788928) };   // 8,388,608 each
    u8*  hhb[2] = { (u8*)(ws + 90177536), (u8*)(ws + 94371840) };   // 4,194,304 each -> ends 98,566,144

    hipFuncSetAttribute((const void*)gemm8<false>, hipFuncAttributeMaxDynamicSharedMemorySize, 81920);
    hipFuncSetAttribute((const void*)gemm8<true>,  hipFuncAttributeMaxDynamicSharedMemorySize, 81920);

    dim3 blk(256,1,1);
    // W prep: qkv/f1 use 128-col images; f2 keeps 256-col
    wsplit_rne<<<dim3(16,4), blk,0,stream>>>(GETP(1),  Bqkv, 512, 0, 16, 128);
    wsplit_rne<<<dim3(16,4), blk,0,stream>>>(GETP(7),  Bqkv, 512, 4, 16, 128);
    wsplit_rne<<<dim3(16,4), blk,0,stream>>>(GETP(13), Bqkv, 512, 8, 16, 128);
    wsplit_rne<<<dim3(16,16),blk,0,stream>>>(GETP(25), Bf1, 2048, 0, 16, 128);
    wsplit_rne<<<dim3(64,2), blk,0,stream>>>(GETP(31), Bf2,  512, 0, 64, 256);
    wsplit_old<<<dim3(8,8),  blk,0,stream>>>(GETP(19), WTp,  512, 512);

    for (int hb = 0; hb < 2; hb++){
        const int pb = hb * PH;
        asplitT<<<dim3(64,16),blk,0,stream>>>(x, At, pb);
        // fused q/k/v (N=1536, NB=12, grid 768)
        gemm8<false><<<dim3(768),dim3(512),81920,stream>>>(At, Bqkv,
            GETP(2),GETP(8),GETP(14),  GETP(3),GETP(9),GETP(15),
            GETP(4),GETP(10),GETP(16), GETP(5),GETP(11),GETP(17),
            GETP(6),GETP(12),GETP(18), qkv, 12, 1536, 511);
        attn_lif_kernel<<<dim3(4,8,16),blk,0,stream>>>(qkv, os_);
        // p stage + fused o2/f1-image production
        gemm_p<<<dim3(4,128),blk,0,stream>>>(os_, WTp,
            GETP(20),GETP(21),GETP(22),GETP(23),GETP(24), x, o2h[hb], At, pb);
        // f1 (N=2048, NB=16, grid 1024, bitpacked out)
        gemm8<true><<<dim3(1024),dim3(512),81920,stream>>>(At, Bf1,
            GETP(26),GETP(26),GETP(26), GETP(27),GETP(27),GETP(27),
            GETP(28),GETP(28),GETP(28), GETP(29),GETP(29),GETP(29),
            GETP(30),GETP(30),GETP(30), hhb[hb], 16, 2048, 2047);
    }
    // f2 v4: both halves, grid 512, T14 staging, coalesced epilogue -> d_out
    gemm8_f2<<<dim3(512),dim3(512),0,stream>>>(hhb[0], hhb[1], Bf2,
        GETP(32),GETP(33),GETP(34),GETP(35),GETP(36), x, o2h[0], o2h[1], (float*)d_out);
}